// Round 3
// baseline (2133.214 us; speedup 1.0000x reference)
//
#include <hip/hip_runtime.h>
#include <cstdint>
#include <cstddef>

// Problem shape (fixed by setup_inputs): B=8, S=2048, D=512. All tensors f32.
#define BATCH 8
#define SEQ   2048
#define DDIM  512
#define NROW  (BATCH*SEQ)          // 16384 token rows
#define KPACK (DDIM/4)             // 128 packed int32 per row
#define EPSQ  1e-5f
#define FSCALE 0.35355339059327373f  // 8 ** -0.5

// Workspace layout (bytes)
static constexpr size_t OFF_M   = 0;                                   // 3 floats abs-sum
static constexpr size_t OFF_WP  = 256;                                 // 3*128*512 int32
static constexpr size_t OFF_XQ  = OFF_WP + (size_t)3*KPACK*DDIM*4;     // 16384*128 int32
static constexpr size_t OFF_SX  = OFF_XQ + (size_t)NROW*KPACK*4;       // 16384 f32
static constexpr size_t OFF_QKV = OFF_SX + (size_t)NROW*4;             // 3*16384*512 f32

#if __has_builtin(__builtin_amdgcn_sdot4)
__device__ __forceinline__ int dot4(int a, int b, int c) {
  return __builtin_amdgcn_sdot4(a, b, c, false);
}
#else
__device__ __forceinline__ int dot4(int a, int b, int c) {
  return c + (int)(signed char)(a & 0xff)        * (int)(signed char)(b & 0xff)
           + (int)(signed char)((a >> 8) & 0xff) * (int)(signed char)((b >> 8) & 0xff)
           + (int)(signed char)((a >> 16) & 0xff)* (int)(signed char)((b >> 16) & 0xff)
           + (int)(signed char)(a >> 24)         * (int)(signed char)(b >> 24);
}
#endif

__device__ __forceinline__ int q8(float v, float s) {
  int i = (int)rintf(v * s);
  i = i < -128 ? -128 : (i > 127 ? 127 : i);
  return i & 0xff;
}

// ---------------------------------------------------------------------------
// 1. abs-sum of each weight matrix. grid (32,3), block 256; mw pre-zeroed.
// ---------------------------------------------------------------------------
__global__ __launch_bounds__(256) void wsum_kernel(
    const float* __restrict__ Wq, const float* __restrict__ Wk,
    const float* __restrict__ Wv, float* __restrict__ mw) {
  const float* W = blockIdx.y == 0 ? Wq : (blockIdx.y == 1 ? Wk : Wv);
  __shared__ float red[256];
  const float4* p = (const float4*)(W + blockIdx.x * 8192);
  float s = 0.f;
  #pragma unroll
  for (int i = 0; i < 8; i++) {
    float4 a = p[i * 256 + threadIdx.x];
    s += fabsf(a.x) + fabsf(a.y) + fabsf(a.z) + fabsf(a.w);
  }
  red[threadIdx.x] = s;
  __syncthreads();
  for (int w = 128; w > 0; w >>= 1) {
    if ((int)threadIdx.x < w) red[threadIdx.x] += red[threadIdx.x + w];
    __syncthreads();
  }
  if (threadIdx.x == 0) atomicAdd(&mw[blockIdx.y], red[0]);
}

// ---------------------------------------------------------------------------
// 2. ternary-quantize weights, packed K-major: wp[mat][k4][o]. grid 768x256.
// ---------------------------------------------------------------------------
__global__ __launch_bounds__(256) void wquant_kernel(
    const float* __restrict__ Wq, const float* __restrict__ Wk,
    const float* __restrict__ Wv, const float* __restrict__ mw,
    int* __restrict__ wp) {
  int idx = blockIdx.x * 256 + threadIdx.x;   // 0 .. 196607
  int mat = idx >> 16;
  int local = idx & 0xFFFF;
  int o  = local >> 7;       // 0..511
  int k4 = local & 127;      // 0..127
  const float* W = mat == 0 ? Wq : (mat == 1 ? Wk : Wv);
  float mean = mw[mat] * (1.0f / 262144.0f);
  float scale = 1.0f / fmaxf(mean, EPSQ);
  float4 w4 = *(const float4*)(W + (size_t)o * DDIM + k4 * 4);
  int t0 = (int)rintf(w4.x * scale); t0 = t0 < -1 ? -1 : (t0 > 1 ? 1 : t0);
  int t1 = (int)rintf(w4.y * scale); t1 = t1 < -1 ? -1 : (t1 > 1 ? 1 : t1);
  int t2 = (int)rintf(w4.z * scale); t2 = t2 < -1 ? -1 : (t2 > 1 ? 1 : t2);
  int t3 = (int)rintf(w4.w * scale); t3 = t3 < -1 ? -1 : (t3 > 1 ? 1 : t3);
  int packed = (t0 & 0xff) | ((t1 & 0xff) << 8) | ((t2 & 0xff) << 16) | ((t3 & 0xff) << 24);
  wp[(size_t)mat * KPACK * DDIM + (size_t)k4 * DDIM + o] = packed;
}

// ---------------------------------------------------------------------------
// 3. per-token int8 absmax quantization. One wave per 512-elem row.
// ---------------------------------------------------------------------------
__global__ __launch_bounds__(256) void aquant_kernel(
    const float* __restrict__ x, int* __restrict__ xq, float* __restrict__ sx) {
  int wid = threadIdx.x >> 6, lane = threadIdx.x & 63;
  int row = blockIdx.x * 4 + wid;
  const float* xr = x + (size_t)row * DDIM;
  float4 a = ((const float4*)xr)[lane];        // k = 4*lane .. +3
  float4 b = ((const float4*)xr)[64 + lane];   // k = 256+4*lane .. +3
  float amax = fmaxf(fmaxf(fmaxf(fabsf(a.x), fabsf(a.y)), fmaxf(fabsf(a.z), fabsf(a.w))),
                     fmaxf(fmaxf(fabsf(b.x), fabsf(b.y)), fmaxf(fabsf(b.z), fabsf(b.w))));
  for (int off = 32; off > 0; off >>= 1) amax = fmaxf(amax, __shfl_xor(amax, off, 64));
  float aa = fmaxf(amax, EPSQ);
  float scale = 127.0f / aa;
  int p0 = q8(a.x, scale) | (q8(a.y, scale) << 8) | (q8(a.z, scale) << 16) | (q8(a.w, scale) << 24);
  int p1 = q8(b.x, scale) | (q8(b.y, scale) << 8) | (q8(b.z, scale) << 16) | (q8(b.w, scale) << 24);
  xq[(size_t)row * KPACK + lane]      = p0;    // k4 = lane
  xq[(size_t)row * KPACK + 64 + lane] = p1;    // k4 = 64+lane
  if (lane == 0) sx[row] = aa * (1.0f / 127.0f);
}

// ---------------------------------------------------------------------------
// 4. int8 x ternary GEMM. grid (1024, 4, 3), block 256.
// ---------------------------------------------------------------------------
__global__ __launch_bounds__(256) void qkv_gemm_kernel(
    const int* __restrict__ xq, const int* __restrict__ wp,
    const float* __restrict__ sx, const float* __restrict__ mw,
    float* __restrict__ qkv) {
  __shared__ int xs[16][KPACK];
  int tid = threadIdx.x;
  int r0  = blockIdx.x * 16;
  int ocl = tid & 127;
  int rg  = tid >> 7;
  int oc  = blockIdx.y * 128 + ocl;
  int mat = blockIdx.z;

  #pragma unroll
  for (int i = 0; i < 8; i++) {
    int e = i * 256 + tid;
    ((int*)xs)[e] = xq[(size_t)r0 * KPACK + e];
  }
  __syncthreads();

  const int* wcol = wp + (size_t)mat * KPACK * DDIM + oc;
  int acc[8] = {0, 0, 0, 0, 0, 0, 0, 0};
  #pragma unroll 4
  for (int k4 = 0; k4 < KPACK; k4++) {
    int wv = wcol[(size_t)k4 * DDIM];
    #pragma unroll
    for (int rr = 0; rr < 8; rr++)
      acc[rr] = dot4(xs[rg * 8 + rr][k4], wv, acc[rr]);
  }
  float mval = fmaxf(mw[mat] * (1.0f / 262144.0f), EPSQ);
  float* outb = qkv + (size_t)mat * NROW * DDIM;
  #pragma unroll
  for (int rr = 0; rr < 8; rr++) {
    int row = r0 + rg * 8 + rr;
    outb[(size_t)row * DDIM + oc] = (float)acc[rr] * sx[row] * mval;
  }
}

// ---------------------------------------------------------------------------
// 5. fp32 flash attention, causal, scale 8^-0.5. BM=16, BN=8. grid (128,8).
//    Output: f32 (reference output dtype).
// ---------------------------------------------------------------------------
__global__ __launch_bounds__(256) void flash_kernel(
    const float* __restrict__ q, const float* __restrict__ k,
    const float* __restrict__ v, float* __restrict__ out) {
  __shared__ float qs[16][516];      // +4 pad: conflict-free b128 reads
  __shared__ float ks[8][DDIM];      // shared K-tile / V-tile buffer
  __shared__ float Ps[16][17];       // [r][2j+h] partials -> probs at [2j]; alpha at [16]
  int tid = threadIdx.x;
  int bq = blockIdx.x, b = blockIdx.y;
  int i0 = bq * 16;
  const size_t bbase = (size_t)b * SEQ * DDIM;
  const float* qb = q + bbase;
  const float* kb = k + bbase;
  const float* vb = v + bbase;

  #pragma unroll
  for (int i = 0; i < 8; i++) {
    int e = i * 256 + tid;
    int row = e >> 7, c4 = e & 127;
    *(float4*)&qs[row][c4 * 4] = ((const float4*)(qb + (size_t)(i0 + row) * DDIM))[c4];
  }

  int sr = tid & 15, sj = (tid >> 4) & 7, sh = tid >> 7;
  int pr = tid & 15, pg = tid >> 4;

  float m_r = -INFINITY, l_r = 0.f;  // live in tid<16
  float4 o4[8];
  #pragma unroll
  for (int i = 0; i < 8; i++) o4[i] = make_float4(0.f, 0.f, 0.f, 0.f);

  int ntiles = 2 * (bq + 1);
  __syncthreads();

  for (int kt = 0; kt < ntiles; kt++) {
    #pragma unroll
    for (int i = 0; i < 4; i++) {
      int e = i * 256 + tid;
      int row = e >> 7, c4 = e & 127;
      *(float4*)&ks[row][c4 * 4] = ((const float4*)(kb + (size_t)(kt * 8 + row) * DDIM))[c4];
    }
    __syncthreads();

    {
      float acc = 0.f;
      const float* qrow = &qs[sr][sh * 256];
      const float* krow = &ks[sj][sh * 256];
      #pragma unroll 4
      for (int c4 = 0; c4 < 64; c4++) {
        float4 qv = *(const float4*)(qrow + c4 * 4);
        float4 kv = *(const float4*)(krow + c4 * 4);
        acc += qv.x * kv.x + qv.y * kv.y + qv.z * kv.z + qv.w * kv.w;
      }
      Ps[sr][sj * 2 + sh] = acc;
    }
    __syncthreads();

    if (tid < 16) {
      int r = tid, ig = i0 + r;
      float mx = m_r;
      float sv[8];
      #pragma unroll
      for (int j = 0; j < 8; j++) {
        float s = (Ps[r][2 * j] + Ps[r][2 * j + 1]) * FSCALE;
        int jg = kt * 8 + j;
        if (jg > ig) s = -INFINITY;
        sv[j] = s;
        mx = fmaxf(mx, s);
      }
      float alpha = expf(m_r - mx);
      float sum = 0.f;
      #pragma unroll
      for (int j = 0; j < 8; j++) {
        float p = expf(sv[j] - mx);
        Ps[r][2 * j] = p;
        sum += p;
      }
      l_r = l_r * alpha + sum;
      m_r = mx;
      Ps[r][16] = alpha;
    }
    #pragma unroll
    for (int i = 0; i < 4; i++) {
      int e = i * 256 + tid;
      int row = e >> 7, c4 = e & 127;
      *(float4*)&ks[row][c4 * 4] = ((const float4*)(vb + (size_t)(kt * 8 + row) * DDIM))[c4];
    }
    __syncthreads();

    {
      float alpha = Ps[pr][16];
      #pragma unroll
      for (int i = 0; i < 8; i++) {
        o4[i].x *= alpha; o4[i].y *= alpha; o4[i].z *= alpha; o4[i].w *= alpha;
      }
      #pragma unroll
      for (int j = 0; j < 8; j++) {
        float p = Ps[pr][2 * j];
        const float4* vrow = (const float4*)&ks[j][pg * 32];
        #pragma unroll
        for (int c4 = 0; c4 < 8; c4++) {
          float4 vv = vrow[c4];
          o4[c4].x += p * vv.x; o4[c4].y += p * vv.y;
          o4[c4].z += p * vv.z; o4[c4].w += p * vv.w;
        }
      }
    }
    __syncthreads();
  }

  if (tid < 16) Ps[tid][16] = 1.0f / l_r;
  __syncthreads();
  float invl = Ps[pr][16];
  float* orow = out + ((size_t)b * SEQ + i0 + pr) * DDIM + pg * 32;
  #pragma unroll
  for (int i = 0; i < 8; i++) {
    float4 w;
    w.x = o4[i].x * invl; w.y = o4[i].y * invl;
    w.z = o4[i].z * invl; w.w = o4[i].w * invl;
    ((float4*)orow)[i] = w;
  }
}

// ---------------------------------------------------------------------------
extern "C" void kernel_launch(void* const* d_in, const int* in_sizes, int n_in,
                              void* d_out, int out_size, void* d_ws, size_t ws_size,
                              hipStream_t stream) {
  const float* x  = (const float*)d_in[0];
  const float* Wq = (const float*)d_in[1];
  const float* Wk = (const float*)d_in[2];
  const float* Wv = (const float*)d_in[3];
  float* out = (float*)d_out;
  char* ws = (char*)d_ws;

  float* mw  = (float*)(ws + OFF_M);
  int*   wp  = (int*)(ws + OFF_WP);
  int*   xq  = (int*)(ws + OFF_XQ);
  float* sx  = (float*)(ws + OFF_SX);
  float* qkv = (float*)(ws + OFF_QKV);
  float* qf  = qkv;
  float* kf  = qkv + (size_t)NROW * DDIM;
  float* vf  = qkv + 2 * (size_t)NROW * DDIM;

  hipMemsetAsync(mw, 0, 16, stream);
  wsum_kernel<<<dim3(32, 3), 256, 0, stream>>>(Wq, Wk, Wv, mw);
  wquant_kernel<<<768, 256, 0, stream>>>(Wq, Wk, Wv, mw, wp);
  aquant_kernel<<<4096, 256, 0, stream>>>(x, xq, sx);
  qkv_gemm_kernel<<<dim3(1024, 4, 3), 256, 0, stream>>>(xq, wp, sx, mw, qkv);
  flash_kernel<<<dim3(128, 8), 256, 0, stream>>>(qf, kf, vf, out);
}

// Round 4
// 533.379 us; speedup vs baseline: 3.9994x; 3.9994x over previous
//
#include <hip/hip_runtime.h>
#include <cstdint>
#include <cstddef>

// Problem shape (fixed by setup_inputs): B=8, S=2048, D=512. All tensors f32.
#define BATCH 8
#define SEQ   2048
#define DDIM  512
#define NROW  (BATCH*SEQ)          // 16384 token rows
#define KPACK (DDIM/4)             // 128 packed int32 per row
#define EPSQ  1e-5f
#define FSCALE 0.35355339059327373f  // 8 ** -0.5

typedef _Float16 half8 __attribute__((ext_vector_type(8)));
typedef float    f32x4 __attribute__((ext_vector_type(4)));

// Workspace layout (bytes)
static constexpr size_t OFF_M   = 0;                                   // 3 floats abs-sum
static constexpr size_t OFF_WP  = 256;                                 // 3*128*512 int32
static constexpr size_t OFF_XQ  = OFF_WP + (size_t)3*KPACK*DDIM*4;     // 16384*128 int32
static constexpr size_t OFF_SX  = OFF_XQ + (size_t)NROW*KPACK*4;       // 16384 f32
static constexpr size_t OFF_QKV = OFF_SX + (size_t)NROW*4;             // 3*16384*512 f16

#if __has_builtin(__builtin_amdgcn_sdot4)
__device__ __forceinline__ int dot4(int a, int b, int c) {
  return __builtin_amdgcn_sdot4(a, b, c, false);
}
#else
__device__ __forceinline__ int dot4(int a, int b, int c) {
  return c + (int)(signed char)(a & 0xff)        * (int)(signed char)(b & 0xff)
           + (int)(signed char)((a >> 8) & 0xff) * (int)(signed char)((b >> 8) & 0xff)
           + (int)(signed char)((a >> 16) & 0xff)* (int)(signed char)((b >> 16) & 0xff)
           + (int)(signed char)(a >> 24)         * (int)(signed char)(b >> 24);
}
#endif

__device__ __forceinline__ int q8(float v, float s) {
  int i = (int)rintf(v * s);
  i = i < -128 ? -128 : (i > 127 ? 127 : i);
  return i & 0xff;
}

// ---------------------------------------------------------------------------
// 1. abs-sum of each weight matrix. grid (32,3), block 256; mw pre-zeroed.
// ---------------------------------------------------------------------------
__global__ __launch_bounds__(256) void wsum_kernel(
    const float* __restrict__ Wq, const float* __restrict__ Wk,
    const float* __restrict__ Wv, float* __restrict__ mw) {
  const float* W = blockIdx.y == 0 ? Wq : (blockIdx.y == 1 ? Wk : Wv);
  __shared__ float red[256];
  const float4* p = (const float4*)(W + blockIdx.x * 8192);
  float s = 0.f;
  #pragma unroll
  for (int i = 0; i < 8; i++) {
    float4 a = p[i * 256 + threadIdx.x];
    s += fabsf(a.x) + fabsf(a.y) + fabsf(a.z) + fabsf(a.w);
  }
  red[threadIdx.x] = s;
  __syncthreads();
  for (int w = 128; w > 0; w >>= 1) {
    if ((int)threadIdx.x < w) red[threadIdx.x] += red[threadIdx.x + w];
    __syncthreads();
  }
  if (threadIdx.x == 0) atomicAdd(&mw[blockIdx.y], red[0]);
}

// ---------------------------------------------------------------------------
// 2. ternary-quantize weights, packed K-major: wp[mat][k4][o]. grid 768x256.
// ---------------------------------------------------------------------------
__global__ __launch_bounds__(256) void wquant_kernel(
    const float* __restrict__ Wq, const float* __restrict__ Wk,
    const float* __restrict__ Wv, const float* __restrict__ mw,
    int* __restrict__ wp) {
  int idx = blockIdx.x * 256 + threadIdx.x;   // 0 .. 196607
  int mat = idx >> 16;
  int local = idx & 0xFFFF;
  int o  = local >> 7;       // 0..511
  int k4 = local & 127;      // 0..127
  const float* W = mat == 0 ? Wq : (mat == 1 ? Wk : Wv);
  float mean = mw[mat] * (1.0f / 262144.0f);
  float scale = 1.0f / fmaxf(mean, EPSQ);
  float4 w4 = *(const float4*)(W + (size_t)o * DDIM + k4 * 4);
  int t0 = (int)rintf(w4.x * scale); t0 = t0 < -1 ? -1 : (t0 > 1 ? 1 : t0);
  int t1 = (int)rintf(w4.y * scale); t1 = t1 < -1 ? -1 : (t1 > 1 ? 1 : t1);
  int t2 = (int)rintf(w4.z * scale); t2 = t2 < -1 ? -1 : (t2 > 1 ? 1 : t2);
  int t3 = (int)rintf(w4.w * scale); t3 = t3 < -1 ? -1 : (t3 > 1 ? 1 : t3);
  int packed = (t0 & 0xff) | ((t1 & 0xff) << 8) | ((t2 & 0xff) << 16) | ((t3 & 0xff) << 24);
  wp[(size_t)mat * KPACK * DDIM + (size_t)k4 * DDIM + o] = packed;
}

// ---------------------------------------------------------------------------
// 3. per-token int8 absmax quantization. One wave per 512-elem row.
// ---------------------------------------------------------------------------
__global__ __launch_bounds__(256) void aquant_kernel(
    const float* __restrict__ x, int* __restrict__ xq, float* __restrict__ sx) {
  int wid = threadIdx.x >> 6, lane = threadIdx.x & 63;
  int row = blockIdx.x * 4 + wid;
  const float* xr = x + (size_t)row * DDIM;
  float4 a = ((const float4*)xr)[lane];        // k = 4*lane .. +3
  float4 b = ((const float4*)xr)[64 + lane];   // k = 256+4*lane .. +3
  float amax = fmaxf(fmaxf(fmaxf(fabsf(a.x), fabsf(a.y)), fmaxf(fabsf(a.z), fabsf(a.w))),
                     fmaxf(fmaxf(fabsf(b.x), fabsf(b.y)), fmaxf(fabsf(b.z), fabsf(b.w))));
  for (int off = 32; off > 0; off >>= 1) amax = fmaxf(amax, __shfl_xor(amax, off, 64));
  float aa = fmaxf(amax, EPSQ);
  float scale = 127.0f / aa;
  int p0 = q8(a.x, scale) | (q8(a.y, scale) << 8) | (q8(a.z, scale) << 16) | (q8(a.w, scale) << 24);
  int p1 = q8(b.x, scale) | (q8(b.y, scale) << 8) | (q8(b.z, scale) << 16) | (q8(b.w, scale) << 24);
  xq[(size_t)row * KPACK + lane]      = p0;    // k4 = lane
  xq[(size_t)row * KPACK + 64 + lane] = p1;    // k4 = 64+lane
  if (lane == 0) sx[row] = aa * (1.0f / 127.0f);
}

// ---------------------------------------------------------------------------
// 4. int8 x ternary GEMM -> f16 output. grid (1024, 4, 3), block 256.
// ---------------------------------------------------------------------------
__global__ __launch_bounds__(256) void qkv_gemm_kernel(
    const int* __restrict__ xq, const int* __restrict__ wp,
    const float* __restrict__ sx, const float* __restrict__ mw,
    _Float16* __restrict__ qkv) {
  __shared__ int xs[16][KPACK];
  int tid = threadIdx.x;
  int r0  = blockIdx.x * 16;
  int ocl = tid & 127;
  int rg  = tid >> 7;
  int oc  = blockIdx.y * 128 + ocl;
  int mat = blockIdx.z;

  #pragma unroll
  for (int i = 0; i < 8; i++) {
    int e = i * 256 + tid;
    ((int*)xs)[e] = xq[(size_t)r0 * KPACK + e];
  }
  __syncthreads();

  const int* wcol = wp + (size_t)mat * KPACK * DDIM + oc;
  int acc[8] = {0, 0, 0, 0, 0, 0, 0, 0};
  #pragma unroll 4
  for (int k4 = 0; k4 < KPACK; k4++) {
    int wv = wcol[(size_t)k4 * DDIM];
    #pragma unroll
    for (int rr = 0; rr < 8; rr++)
      acc[rr] = dot4(xs[rg * 8 + rr][k4], wv, acc[rr]);
  }
  float mval = fmaxf(mw[mat] * (1.0f / 262144.0f), EPSQ);
  _Float16* outb = qkv + (size_t)mat * NROW * DDIM;
  #pragma unroll
  for (int rr = 0; rr < 8; rr++) {
    int row = r0 + rg * 8 + rr;
    outb[(size_t)row * DDIM + oc] = (_Float16)((float)acc[rr] * sx[row] * mval);
  }
}

// ---------------------------------------------------------------------------
// 5. f16 MFMA flash attention, causal, scale 8^-0.5.
//    Block = 256 thr (4 waves). BM=64 (16 q-rows/wave), BN=32 keys/tile.
//    Each block runs two complementary Q-tiles: (batch, qi) and (batch^1, 31-qi)
//    -> uniform 66 K-tiles/block across 256 blocks.
//    MFMA layouts (gfx950, HW-verified): A[m=lane&15][k=quad*8+j],
//    B[k=quad*8+j][n=lane&15], C/D col=lane&15 row=quad*4+reg.
// ---------------------------------------------------------------------------
__global__ __launch_bounds__(256, 1) void flash_kernel(
    const _Float16* __restrict__ q, const _Float16* __restrict__ k,
    const _Float16* __restrict__ v, float* __restrict__ out) {
  __shared__ _Float16 Ksh[32][520];   // [key][dim], pad 8: 2-way-free banks
  __shared__ _Float16 Vt[512][40];    // [dim][key], pad 8
  __shared__ _Float16 Psh[64][40];    // [row][key], pad 8
  __shared__ float alpha_l[64];
  __shared__ float invl_l[64];

  const int tid  = threadIdx.x;
  const int w    = tid >> 6;          // wave 0..3
  const int lane = tid & 63;
  const int quad = lane >> 4;         // 0..3
  const int col  = lane & 15;

  const int qi    = blockIdx.x;       // 0..31
  const int batch = blockIdx.y;       // 0..7

  // staging maps
  const int skey = tid >> 3, schunk = (tid & 7) * 64;    // K staging
  const int vkg  = tid & 3,  vdg = tid >> 2;             // V transpose staging

  for (int ph = 0; ph < 2; ph++) {
    const int qt = ph ? (31 - qi) : qi;
    const int bb = ph ? (batch ^ 1) : batch;
    const int qrow0 = qt * 64;
    const size_t bbase = (size_t)bb * SEQ * DDIM;

    // Q A-frags in registers: wave w owns rows qrow0 + w*16 + col
    half8 qfrag[16];
    {
      const _Float16* qrow = q + bbase + (size_t)(qrow0 + w * 16 + col) * DDIM;
      #pragma unroll
      for (int s = 0; s < 16; s++)
        qfrag[s] = *(const half8*)(qrow + s * 32 + quad * 8);
    }

    f32x4 mreg, lreg;
    #pragma unroll
    for (int e = 0; e < 4; e++) { mreg[e] = -INFINITY; lreg[e] = 0.f; }
    f32x4 o[4][8];
    #pragma unroll
    for (int rt = 0; rt < 4; rt++)
      #pragma unroll
      for (int ct = 0; ct < 8; ct++)
        o[rt][ct] = (f32x4)(0.f);

    const int ntiles = 2 * (qt + 1);
    for (int kt = 0; kt < ntiles; kt++) {
      const int kb = kt * 32;

      // ---- stage K tile [32][512] ----
      {
        const _Float16* krow = k + bbase + (size_t)(kb + skey) * DDIM + schunk;
        #pragma unroll
        for (int i = 0; i < 8; i++)
          *(half8*)&Ksh[skey][schunk + i * 8] = *(const half8*)(krow + i * 8);
      }
      // ---- stage V transposed: Vt[dim][key] ----
      {
        const _Float16* vbase = v + bbase + (size_t)(kb + vkg * 8) * DDIM + vdg * 8;
        half8 r[8];
        #pragma unroll
        for (int kk = 0; kk < 8; kk++)
          r[kk] = *(const half8*)(vbase + (size_t)kk * DDIM);
        #pragma unroll
        for (int dd = 0; dd < 8; dd++) {
          half8 wv;
          #pragma unroll
          for (int kk = 0; kk < 8; kk++) wv[kk] = r[kk][dd];
          *(half8*)&Vt[vdg * 8 + dd][vkg * 8] = wv;
        }
      }
      __syncthreads();

      // ---- scores: wave w computes rows w*16..+15 x keys kb..kb+31 ----
      f32x4 c0 = (f32x4)(0.f), c1 = (f32x4)(0.f);
      #pragma unroll
      for (int s = 0; s < 16; s++) {
        half8 b0 = *(const half8*)&Ksh[col][s * 32 + quad * 8];
        half8 b1 = *(const half8*)&Ksh[col + 16][s * 32 + quad * 8];
        c0 = __builtin_amdgcn_mfma_f32_16x16x32_f16(qfrag[s], b0, c0, 0, 0, 0);
        c1 = __builtin_amdgcn_mfma_f32_16x16x32_f16(qfrag[s], b1, c1, 0, 0, 0);
      }

      // ---- online softmax (per wave, rows quad*4+reg) ----
      #pragma unroll
      for (int reg = 0; reg < 4; reg++) {
        int ig = qrow0 + w * 16 + quad * 4 + reg;
        float s0 = c0[reg] * FSCALE;
        float s1 = c1[reg] * FSCALE;
        if (kb + col > ig)      s0 = -INFINITY;
        if (kb + 16 + col > ig) s1 = -INFINITY;
        float t = fmaxf(s0, s1);
        #pragma unroll
        for (int m = 1; m <= 8; m <<= 1) t = fmaxf(t, __shfl_xor(t, m, 64));
        float mn = fmaxf(mreg[reg], t);
        float al = __expf(mreg[reg] - mn);
        float p0 = __expf(s0 - mn);
        float p1 = __expf(s1 - mn);
        float rs = p0 + p1;
        #pragma unroll
        for (int m = 1; m <= 8; m <<= 1) rs += __shfl_xor(rs, m, 64);
        lreg[reg] = lreg[reg] * al + rs;
        mreg[reg] = mn;
        int prow = w * 16 + quad * 4 + reg;
        Psh[prow][col]      = (_Float16)p0;
        Psh[prow][col + 16] = (_Float16)p1;
        if (col == 0) alpha_l[prow] = al;
      }
      __syncthreads();

      // ---- PV: wave w owns dims 128w..128w+127 for all 64 rows ----
      {
        const int d0 = w * 128;
        f32x4 af[4];
        half8 ap[4];
        #pragma unroll
        for (int rt = 0; rt < 4; rt++) {
          af[rt] = *(const f32x4*)&alpha_l[rt * 16 + quad * 4];
          ap[rt] = *(const half8*)&Psh[rt * 16 + col][quad * 8];
        }
        #pragma unroll
        for (int rt = 0; rt < 4; rt++)
          #pragma unroll
          for (int ct = 0; ct < 8; ct++)
            o[rt][ct] *= af[rt];
        #pragma unroll
        for (int ct = 0; ct < 8; ct++) {
          half8 bv = *(const half8*)&Vt[d0 + ct * 16 + col][quad * 8];
          #pragma unroll
          for (int rt = 0; rt < 4; rt++)
            o[rt][ct] = __builtin_amdgcn_mfma_f32_16x16x32_f16(ap[rt], bv, o[rt][ct], 0, 0, 0);
        }
      }
      __syncthreads();
    }

    // ---- finalize: 1/l broadcast, scale, store ----
    #pragma unroll
    for (int reg = 0; reg < 4; reg++) {
      if (col == 0) invl_l[w * 16 + quad * 4 + reg] = 1.0f / lreg[reg];
    }
    __syncthreads();
    {
      const int d0 = w * 128;
      #pragma unroll
      for (int rt = 0; rt < 4; rt++) {
        f32x4 iv = *(const f32x4*)&invl_l[rt * 16 + quad * 4];
        #pragma unroll
        for (int ct = 0; ct < 8; ct++) {
          #pragma unroll
          for (int e = 0; e < 4; e++) {
            out[((size_t)bb * SEQ + qrow0 + rt * 16 + quad * 4 + e) * DDIM
                + d0 + ct * 16 + col] = o[rt][ct][e] * iv[e];
          }
        }
      }
    }
    __syncthreads();
  }
}

// ---------------------------------------------------------------------------
extern "C" void kernel_launch(void* const* d_in, const int* in_sizes, int n_in,
                              void* d_out, int out_size, void* d_ws, size_t ws_size,
                              hipStream_t stream) {
  const float* x  = (const float*)d_in[0];
  const float* Wq = (const float*)d_in[1];
  const float* Wk = (const float*)d_in[2];
  const float* Wv = (const float*)d_in[3];
  float* out = (float*)d_out;
  char* ws = (char*)d_ws;

  float* mw  = (float*)(ws + OFF_M);
  int*   wp  = (int*)(ws + OFF_WP);
  int*   xq  = (int*)(ws + OFF_XQ);
  float* sx  = (float*)(ws + OFF_SX);
  _Float16* qkv = (_Float16*)(ws + OFF_QKV);
  _Float16* qf  = qkv;
  _Float16* kf  = qkv + (size_t)NROW * DDIM;
  _Float16* vf  = qkv + 2 * (size_t)NROW * DDIM;

  hipMemsetAsync(mw, 0, 16, stream);
  wsum_kernel<<<dim3(32, 3), 256, 0, stream>>>(Wq, Wk, Wv, mw);
  wquant_kernel<<<768, 256, 0, stream>>>(Wq, Wk, Wv, mw, wp);
  aquant_kernel<<<4096, 256, 0, stream>>>(x, xq, sx);
  qkv_gemm_kernel<<<dim3(1024, 4, 3), 256, 0, stream>>>(xq, wp, sx, mw, qkv);
  flash_kernel<<<dim3(32, 8), 256, 0, stream>>>(qf, kf, vf, out);
}

// Round 5
// 391.974 us; speedup vs baseline: 5.4422x; 1.3608x over previous
//
#include <hip/hip_runtime.h>
#include <cstdint>
#include <cstddef>

// Problem shape (fixed by setup_inputs): B=8, S=2048, D=512. All tensors f32.
#define BATCH 8
#define SEQ   2048
#define DDIM  512
#define NROW  (BATCH*SEQ)          // 16384 token rows
#define KPACK (DDIM/4)             // 128 packed int32 per row
#define EPSQ  1e-5f
#define FSCALE 0.35355339059327373f  // 8 ** -0.5

typedef _Float16 half8 __attribute__((ext_vector_type(8)));
typedef _Float16 half4 __attribute__((ext_vector_type(4)));
typedef float    f32x4 __attribute__((ext_vector_type(4)));

// Workspace layout (bytes)
static constexpr size_t OFF_M   = 0;                                   // 3 floats abs-sum
static constexpr size_t OFF_WP  = 256;                                 // 3*128*512 int32
static constexpr size_t OFF_XQ  = OFF_WP + (size_t)3*KPACK*DDIM*4;     // 16384*128 int32
static constexpr size_t OFF_SX  = OFF_XQ + (size_t)NROW*KPACK*4;       // 16384 f32
static constexpr size_t OFF_QKV = OFF_SX + (size_t)NROW*4;             // 3*16384*512 f16

#if __has_builtin(__builtin_amdgcn_sdot4)
__device__ __forceinline__ int dot4(int a, int b, int c) {
  return __builtin_amdgcn_sdot4(a, b, c, false);
}
#else
__device__ __forceinline__ int dot4(int a, int b, int c) {
  return c + (int)(signed char)(a & 0xff)        * (int)(signed char)(b & 0xff)
           + (int)(signed char)((a >> 8) & 0xff) * (int)(signed char)((b >> 8) & 0xff)
           + (int)(signed char)((a >> 16) & 0xff)* (int)(signed char)((b >> 16) & 0xff)
           + (int)(signed char)(a >> 24)         * (int)(signed char)(b >> 24);
}
#endif

__device__ __forceinline__ int q8(float v, float s) {
  int i = (int)rintf(v * s);
  i = i < -128 ? -128 : (i > 127 ? 127 : i);
  return i & 0xff;
}

// async global->LDS DMA, 16B per lane; lds dest = wave-uniform base + lane*16
__device__ __forceinline__ void gld_lds16(const _Float16* g, _Float16* l) {
  __builtin_amdgcn_global_load_lds(
      (const __attribute__((address_space(1))) void*)g,
      (__attribute__((address_space(3))) void*)l, 16, 0, 0);
}

// ---------------------------------------------------------------------------
// 1. abs-sum of each weight matrix. grid (32,3), block 256; mw pre-zeroed.
// ---------------------------------------------------------------------------
__global__ __launch_bounds__(256) void wsum_kernel(
    const float* __restrict__ Wq, const float* __restrict__ Wk,
    const float* __restrict__ Wv, float* __restrict__ mw) {
  const float* W = blockIdx.y == 0 ? Wq : (blockIdx.y == 1 ? Wk : Wv);
  __shared__ float red[256];
  const float4* p = (const float4*)(W + blockIdx.x * 8192);
  float s = 0.f;
  #pragma unroll
  for (int i = 0; i < 8; i++) {
    float4 a = p[i * 256 + threadIdx.x];
    s += fabsf(a.x) + fabsf(a.y) + fabsf(a.z) + fabsf(a.w);
  }
  red[threadIdx.x] = s;
  __syncthreads();
  for (int w = 128; w > 0; w >>= 1) {
    if ((int)threadIdx.x < w) red[threadIdx.x] += red[threadIdx.x + w];
    __syncthreads();
  }
  if (threadIdx.x == 0) atomicAdd(&mw[blockIdx.y], red[0]);
}

// ---------------------------------------------------------------------------
// 2. ternary-quantize weights, packed K-major: wp[mat][k4][o]. grid 768x256.
// ---------------------------------------------------------------------------
__global__ __launch_bounds__(256) void wquant_kernel(
    const float* __restrict__ Wq, const float* __restrict__ Wk,
    const float* __restrict__ Wv, const float* __restrict__ mw,
    int* __restrict__ wp) {
  int idx = blockIdx.x * 256 + threadIdx.x;   // 0 .. 196607
  int mat = idx >> 16;
  int local = idx & 0xFFFF;
  int o  = local >> 7;       // 0..511
  int k4 = local & 127;      // 0..127
  const float* W = mat == 0 ? Wq : (mat == 1 ? Wk : Wv);
  float mean = mw[mat] * (1.0f / 262144.0f);
  float scale = 1.0f / fmaxf(mean, EPSQ);
  float4 w4 = *(const float4*)(W + (size_t)o * DDIM + k4 * 4);
  int t0 = (int)rintf(w4.x * scale); t0 = t0 < -1 ? -1 : (t0 > 1 ? 1 : t0);
  int t1 = (int)rintf(w4.y * scale); t1 = t1 < -1 ? -1 : (t1 > 1 ? 1 : t1);
  int t2 = (int)rintf(w4.z * scale); t2 = t2 < -1 ? -1 : (t2 > 1 ? 1 : t2);
  int t3 = (int)rintf(w4.w * scale); t3 = t3 < -1 ? -1 : (t3 > 1 ? 1 : t3);
  int packed = (t0 & 0xff) | ((t1 & 0xff) << 8) | ((t2 & 0xff) << 16) | ((t3 & 0xff) << 24);
  wp[(size_t)mat * KPACK * DDIM + (size_t)k4 * DDIM + o] = packed;
}

// ---------------------------------------------------------------------------
// 3. per-token int8 absmax quantization. One wave per 512-elem row.
// ---------------------------------------------------------------------------
__global__ __launch_bounds__(256) void aquant_kernel(
    const float* __restrict__ x, int* __restrict__ xq, float* __restrict__ sx) {
  int wid = threadIdx.x >> 6, lane = threadIdx.x & 63;
  int row = blockIdx.x * 4 + wid;
  const float* xr = x + (size_t)row * DDIM;
  float4 a = ((const float4*)xr)[lane];        // k = 4*lane .. +3
  float4 b = ((const float4*)xr)[64 + lane];   // k = 256+4*lane .. +3
  float amax = fmaxf(fmaxf(fmaxf(fabsf(a.x), fabsf(a.y)), fmaxf(fabsf(a.z), fabsf(a.w))),
                     fmaxf(fmaxf(fabsf(b.x), fabsf(b.y)), fmaxf(fabsf(b.z), fabsf(b.w))));
  for (int off = 32; off > 0; off >>= 1) amax = fmaxf(amax, __shfl_xor(amax, off, 64));
  float aa = fmaxf(amax, EPSQ);
  float scale = 127.0f / aa;
  int p0 = q8(a.x, scale) | (q8(a.y, scale) << 8) | (q8(a.z, scale) << 16) | (q8(a.w, scale) << 24);
  int p1 = q8(b.x, scale) | (q8(b.y, scale) << 8) | (q8(b.z, scale) << 16) | (q8(b.w, scale) << 24);
  xq[(size_t)row * KPACK + lane]      = p0;    // k4 = lane
  xq[(size_t)row * KPACK + 64 + lane] = p1;    // k4 = 64+lane
  if (lane == 0) sx[row] = aa * (1.0f / 127.0f);
}

// ---------------------------------------------------------------------------
// 4. int8 x ternary GEMM -> f16 output. grid (1024, 4, 3), block 256.
// ---------------------------------------------------------------------------
__global__ __launch_bounds__(256) void qkv_gemm_kernel(
    const int* __restrict__ xq, const int* __restrict__ wp,
    const float* __restrict__ sx, const float* __restrict__ mw,
    _Float16* __restrict__ qkv) {
  __shared__ int xs[16][KPACK];
  int tid = threadIdx.x;
  int r0  = blockIdx.x * 16;
  int ocl = tid & 127;
  int rg  = tid >> 7;
  int oc  = blockIdx.y * 128 + ocl;
  int mat = blockIdx.z;

  #pragma unroll
  for (int i = 0; i < 8; i++) {
    int e = i * 256 + tid;
    ((int*)xs)[e] = xq[(size_t)r0 * KPACK + e];
  }
  __syncthreads();

  const int* wcol = wp + (size_t)mat * KPACK * DDIM + oc;
  int acc[8] = {0, 0, 0, 0, 0, 0, 0, 0};
  #pragma unroll 4
  for (int k4 = 0; k4 < KPACK; k4++) {
    int wv = wcol[(size_t)k4 * DDIM];
    #pragma unroll
    for (int rr = 0; rr < 8; rr++)
      acc[rr] = dot4(xs[rg * 8 + rr][k4], wv, acc[rr]);
  }
  float mval = fmaxf(mw[mat] * (1.0f / 262144.0f), EPSQ);
  _Float16* outb = qkv + (size_t)mat * NROW * DDIM;
  #pragma unroll
  for (int rr = 0; rr < 8; rr++) {
    int row = r0 + rg * 8 + rr;
    outb[(size_t)row * DDIM + oc] = (_Float16)((float)acc[rr] * sx[row] * mval);
  }
}

// ---------------------------------------------------------------------------
// 5. f16 MFMA flash attention, causal, scale 8^-0.5.
//    512 thr = 8 waves, BM=64, BN=32, grid (32,8), 2 complementary phases.
//    K: async DMA double-buffer. V: register prefetch + transposed LDS.
//    Scores: wave (rt=w&3, kh=w>>2). Softmax: 8 threads/row. PV: wave w owns
//    dims w*64..+63. MFMA layouts identical to round-4 (bench-verified).
// ---------------------------------------------------------------------------
__global__ __launch_bounds__(512, 2) void flash_kernel(
    const _Float16* __restrict__ q, const _Float16* __restrict__ k,
    const _Float16* __restrict__ v, float* __restrict__ out) {
  __shared__ __align__(16) _Float16 Ksh[2][32][520];  // [buf][key][dim], row=1040B (16B-mult)
  __shared__ __align__(16) _Float16 Vt[512][36];      // [dim][key], b64 access
  __shared__ __align__(16) float    Ps32[64][33];     // raw scores
  __shared__ __align__(16) _Float16 Pf16[64][36];     // probabilities
  __shared__ __align__(16) float alpha_l[64];
  __shared__ __align__(16) float invl_l[64];

  const int tid  = threadIdx.x;
  const int w    = tid >> 6;        // 0..7
  const int lane = tid & 63;
  const int quad = lane >> 4;
  const int col  = lane & 15;
  const int rt   = w & 3;           // score row-tile
  const int kh   = w >> 2;          // score key-half
  const int smrow = tid >> 3;       // softmax row 0..63
  const int sme   = tid & 7;        // softmax elem group 0..7
  const int vkg = tid & 7;          // V stage: keys vkg*4..+3
  const int vdg = tid >> 3;         // V stage: dims vdg*8..+7
  const int d0  = w * 64;           // PV dim slice

  const int qi = blockIdx.x, batch = blockIdx.y;

  for (int ph = 0; ph < 2; ph++) {
    const int qt = ph ? (31 - qi) : qi;
    const int bb = ph ? (batch ^ 1) : batch;
    const int qrow0 = qt * 64;
    const size_t bbase = (size_t)bb * SEQ * DDIM;
    const _Float16* kb_p = k + bbase;
    const _Float16* vb_p = v + bbase;

    // Q A-frags in registers (rows qrow0 + rt*16 + col)
    half8 qfrag[16];
    {
      const _Float16* qrow_p = q + bbase + (size_t)(qrow0 + rt * 16 + col) * DDIM;
      #pragma unroll
      for (int s = 0; s < 16; s++)
        qfrag[s] = *(const half8*)(qrow_p + s * 32 + quad * 8);
    }

    float m_run = -INFINITY, l_run = 0.f;
    f32x4 o[4][4];
    #pragma unroll
    for (int a = 0; a < 4; a++)
      #pragma unroll
      for (int b = 0; b < 4; b++) o[a][b] = (f32x4)(0.f);

    const int ntiles = 2 * (qt + 1);

    // prologue: V regs tile 0 + DMA K tile 0 -> Ksh[0]
    half8 vr[4];
    {
      const _Float16* vp = vb_p + (size_t)(vkg * 4) * DDIM + vdg * 8;
      #pragma unroll
      for (int j = 0; j < 4; j++) vr[j] = *(const half8*)(vp + (size_t)j * DDIM);
    }
    #pragma unroll
    for (int i = 0; i < 4; i++)
      gld_lds16(kb_p + (size_t)(w * 4 + i) * DDIM + lane * 8, &Ksh[0][w * 4 + i][0]);
    __syncthreads();   // drains DMA K0 + vr

    for (int kt = 0; kt < ntiles; kt++) {
      const int cur = kt & 1, nxt = cur ^ 1;
      const int kb0 = kt * 32;

      // write Vt <- vr (tile kt); safe: last PV read ended at previous barrier
      #pragma unroll
      for (int d = 0; d < 8; d++) {
        half4 t4;
        #pragma unroll
        for (int j = 0; j < 4; j++) t4[j] = vr[j][d];
        *(half4*)&Vt[vdg * 8 + d][vkg * 4] = t4;
      }

      // prefetch tile kt+1 (stays in flight through the scores phase)
      if (kt + 1 < ntiles) {
        const int kb1 = kb0 + 32;
        #pragma unroll
        for (int i = 0; i < 4; i++)
          gld_lds16(kb_p + (size_t)(kb1 + w * 4 + i) * DDIM + lane * 8,
                    &Ksh[nxt][w * 4 + i][0]);
        const _Float16* vp = vb_p + (size_t)(kb1 + vkg * 4) * DDIM + vdg * 8;
        #pragma unroll
        for (int j = 0; j < 4; j++) vr[j] = *(const half8*)(vp + (size_t)j * DDIM);
      }

      // ---- scores: wave (rt,kh): rows rt*16..+15 x keys kb0+kh*16..+15 ----
      {
        f32x4 c0 = (f32x4)(0.f), c1 = (f32x4)(0.f);
        #pragma unroll
        for (int s = 0; s < 16; s += 2) {
          half8 b0 = *(const half8*)&Ksh[cur][kh * 16 + col][s * 32 + quad * 8];
          half8 b1 = *(const half8*)&Ksh[cur][kh * 16 + col][(s + 1) * 32 + quad * 8];
          c0 = __builtin_amdgcn_mfma_f32_16x16x32_f16(qfrag[s], b0, c0, 0, 0, 0);
          c1 = __builtin_amdgcn_mfma_f32_16x16x32_f16(qfrag[s + 1], b1, c1, 0, 0, 0);
        }
        f32x4 c = c0 + c1;
        #pragma unroll
        for (int reg = 0; reg < 4; reg++)
          Ps32[rt * 16 + quad * 4 + reg][kh * 16 + col] = c[reg];
      }
      __syncthreads();   // B1: scores ready (drains prefetch too)

      // ---- softmax: thread (smrow, sme) handles keys sme*4..+3 ----
      {
        const int qrow = qrow0 + smrow;
        float sv[4];
        #pragma unroll
        for (int i = 0; i < 4; i++) {
          float s = Ps32[smrow][sme * 4 + i] * FSCALE;
          if (kb0 + sme * 4 + i > qrow) s = -INFINITY;
          sv[i] = s;
        }
        float mx = fmaxf(fmaxf(sv[0], sv[1]), fmaxf(sv[2], sv[3]));
        #pragma unroll
        for (int m = 1; m <= 4; m <<= 1) mx = fmaxf(mx, __shfl_xor(mx, m, 64));
        float mn = fmaxf(m_run, mx);
        float al = __expf(m_run - mn);
        half4 p4;
        float rs = 0.f;
        #pragma unroll
        for (int i = 0; i < 4; i++) {
          float p = __expf(sv[i] - mn);
          rs += p;
          p4[i] = (_Float16)p;
        }
        #pragma unroll
        for (int m = 1; m <= 4; m <<= 1) rs += __shfl_xor(rs, m, 64);
        l_run = l_run * al + rs;
        m_run = mn;
        *(half4*)&Pf16[smrow][sme * 4] = p4;
        if (sme == 0) alpha_l[smrow] = al;
      }
      __syncthreads();   // B2: Pf16 + alpha ready

      // ---- PV: wave w owns dims d0..d0+63 for all 64 rows ----
      {
        half8 ap[4];
        f32x4 af[4];
        #pragma unroll
        for (int r2 = 0; r2 < 4; r2++) {
          half4 lo = *(const half4*)&Pf16[r2 * 16 + col][quad * 8];
          half4 hi = *(const half4*)&Pf16[r2 * 16 + col][quad * 8 + 4];
          #pragma unroll
          for (int z = 0; z < 4; z++) { ap[r2][z] = lo[z]; ap[r2][z + 4] = hi[z]; }
          af[r2] = *(const f32x4*)&alpha_l[r2 * 16 + quad * 4];
        }
        #pragma unroll
        for (int r2 = 0; r2 < 4; r2++)
          #pragma unroll
          for (int ct = 0; ct < 4; ct++)
            o[r2][ct] *= af[r2];
        #pragma unroll
        for (int ct = 0; ct < 4; ct++) {
          half4 blo = *(const half4*)&Vt[d0 + ct * 16 + col][quad * 8];
          half4 bhi = *(const half4*)&Vt[d0 + ct * 16 + col][quad * 8 + 4];
          half8 bv;
          #pragma unroll
          for (int z = 0; z < 4; z++) { bv[z] = blo[z]; bv[z + 4] = bhi[z]; }
          #pragma unroll
          for (int r2 = 0; r2 < 4; r2++)
            o[r2][ct] = __builtin_amdgcn_mfma_f32_16x16x32_f16(ap[r2], bv, o[r2][ct], 0, 0, 0);
        }
      }
      __syncthreads();   // B3: PV done; Vt/Pf16/alpha reusable next tile
    }

    // ---- finalize ----
    if (sme == 0) invl_l[smrow] = 1.0f / l_run;
    __syncthreads();
    #pragma unroll
    for (int r2 = 0; r2 < 4; r2++) {
      f32x4 iv = *(const f32x4*)&invl_l[r2 * 16 + quad * 4];
      #pragma unroll
      for (int ct = 0; ct < 4; ct++) {
        #pragma unroll
        for (int e = 0; e < 4; e++) {
          out[((size_t)bb * SEQ + qrow0 + r2 * 16 + quad * 4 + e) * DDIM
              + d0 + ct * 16 + col] = o[r2][ct][e] * iv[e];
        }
      }
    }
    __syncthreads();   // protect LDS before next phase's prologue
  }
}

// ---------------------------------------------------------------------------
extern "C" void kernel_launch(void* const* d_in, const int* in_sizes, int n_in,
                              void* d_out, int out_size, void* d_ws, size_t ws_size,
                              hipStream_t stream) {
  const float* x  = (const float*)d_in[0];
  const float* Wq = (const float*)d_in[1];
  const float* Wk = (const float*)d_in[2];
  const float* Wv = (const float*)d_in[3];
  float* out = (float*)d_out;
  char* ws = (char*)d_ws;

  float* mw  = (float*)(ws + OFF_M);
  int*   wp  = (int*)(ws + OFF_WP);
  int*   xq  = (int*)(ws + OFF_XQ);
  float* sx  = (float*)(ws + OFF_SX);
  _Float16* qkv = (_Float16*)(ws + OFF_QKV);
  _Float16* qf  = qkv;
  _Float16* kf  = qkv + (size_t)NROW * DDIM;
  _Float16* vf  = qkv + 2 * (size_t)NROW * DDIM;

  hipMemsetAsync(mw, 0, 16, stream);
  wsum_kernel<<<dim3(32, 3), 256, 0, stream>>>(Wq, Wk, Wv, mw);
  wquant_kernel<<<768, 256, 0, stream>>>(Wq, Wk, Wv, mw, wp);
  aquant_kernel<<<4096, 256, 0, stream>>>(x, xq, sx);
  qkv_gemm_kernel<<<dim3(1024, 4, 3), 256, 0, stream>>>(xq, wp, sx, mw, qkv);
  flash_kernel<<<dim3(32, 8), 512, 0, stream>>>(qf, kf, vf, out);
}

// Round 6
// 381.064 us; speedup vs baseline: 5.5980x; 1.0286x over previous
//
#include <hip/hip_runtime.h>
#include <cstdint>
#include <cstddef>

// Problem shape (fixed by setup_inputs): B=8, S=2048, D=512. All tensors f32.
#define BATCH 8
#define SEQ   2048
#define DDIM  512
#define NROW  (BATCH*SEQ)          // 16384 token rows
#define KPACK (DDIM/4)             // 128 packed int32 per row
#define EPSQ  1e-5f
#define FSCALE 0.35355339059327373f  // 8 ** -0.5

typedef _Float16 half8 __attribute__((ext_vector_type(8)));
typedef _Float16 half4 __attribute__((ext_vector_type(4)));
typedef float    f32x4 __attribute__((ext_vector_type(4)));

// Workspace layout (bytes)
static constexpr size_t OFF_M   = 0;                                   // 3 floats abs-sum
static constexpr size_t OFF_WP  = 256;                                 // 3*128*512 int32
static constexpr size_t OFF_XQ  = OFF_WP + (size_t)3*KPACK*DDIM*4;     // 16384*128 int32
static constexpr size_t OFF_SX  = OFF_XQ + (size_t)NROW*KPACK*4;       // 16384 f32
static constexpr size_t OFF_QKV = OFF_SX + (size_t)NROW*4;             // 3*16384*512 f16

#if __has_builtin(__builtin_amdgcn_sdot4)
__device__ __forceinline__ int dot4(int a, int b, int c) {
  return __builtin_amdgcn_sdot4(a, b, c, false);
}
#else
__device__ __forceinline__ int dot4(int a, int b, int c) {
  return c + (int)(signed char)(a & 0xff)        * (int)(signed char)(b & 0xff)
           + (int)(signed char)((a >> 8) & 0xff) * (int)(signed char)((b >> 8) & 0xff)
           + (int)(signed char)((a >> 16) & 0xff)* (int)(signed char)((b >> 16) & 0xff)
           + (int)(signed char)(a >> 24)         * (int)(signed char)(b >> 24);
}
#endif

__device__ __forceinline__ int q8(float v, float s) {
  int i = (int)rintf(v * s);
  i = i < -128 ? -128 : (i > 127 ? 127 : i);
  return i & 0xff;
}

// async global->LDS DMA, 16B per lane; lds dest = wave-uniform base + lane*16
__device__ __forceinline__ void gld_lds16(const _Float16* g, _Float16* l) {
  __builtin_amdgcn_global_load_lds(
      (const __attribute__((address_space(1))) void*)g,
      (__attribute__((address_space(3))) void*)l, 16, 0, 0);
}

// ---------------------------------------------------------------------------
// 1. abs-sum of each weight matrix. grid (32,3), block 256; mw pre-zeroed.
// ---------------------------------------------------------------------------
__global__ __launch_bounds__(256) void wsum_kernel(
    const float* __restrict__ Wq, const float* __restrict__ Wk,
    const float* __restrict__ Wv, float* __restrict__ mw) {
  const float* W = blockIdx.y == 0 ? Wq : (blockIdx.y == 1 ? Wk : Wv);
  __shared__ float red[256];
  const float4* p = (const float4*)(W + blockIdx.x * 8192);
  float s = 0.f;
  #pragma unroll
  for (int i = 0; i < 8; i++) {
    float4 a = p[i * 256 + threadIdx.x];
    s += fabsf(a.x) + fabsf(a.y) + fabsf(a.z) + fabsf(a.w);
  }
  red[threadIdx.x] = s;
  __syncthreads();
  for (int w = 128; w > 0; w >>= 1) {
    if ((int)threadIdx.x < w) red[threadIdx.x] += red[threadIdx.x + w];
    __syncthreads();
  }
  if (threadIdx.x == 0) atomicAdd(&mw[blockIdx.y], red[0]);
}

// ---------------------------------------------------------------------------
// 2. ternary-quantize weights, packed K-major: wp[mat][k4][o]. grid 768x256.
// ---------------------------------------------------------------------------
__global__ __launch_bounds__(256) void wquant_kernel(
    const float* __restrict__ Wq, const float* __restrict__ Wk,
    const float* __restrict__ Wv, const float* __restrict__ mw,
    int* __restrict__ wp) {
  int idx = blockIdx.x * 256 + threadIdx.x;   // 0 .. 196607
  int mat = idx >> 16;
  int local = idx & 0xFFFF;
  int o  = local >> 7;       // 0..511
  int k4 = local & 127;      // 0..127
  const float* W = mat == 0 ? Wq : (mat == 1 ? Wk : Wv);
  float mean = mw[mat] * (1.0f / 262144.0f);
  float scale = 1.0f / fmaxf(mean, EPSQ);
  float4 w4 = *(const float4*)(W + (size_t)o * DDIM + k4 * 4);
  int t0 = (int)rintf(w4.x * scale); t0 = t0 < -1 ? -1 : (t0 > 1 ? 1 : t0);
  int t1 = (int)rintf(w4.y * scale); t1 = t1 < -1 ? -1 : (t1 > 1 ? 1 : t1);
  int t2 = (int)rintf(w4.z * scale); t2 = t2 < -1 ? -1 : (t2 > 1 ? 1 : t2);
  int t3 = (int)rintf(w4.w * scale); t3 = t3 < -1 ? -1 : (t3 > 1 ? 1 : t3);
  int packed = (t0 & 0xff) | ((t1 & 0xff) << 8) | ((t2 & 0xff) << 16) | ((t3 & 0xff) << 24);
  wp[(size_t)mat * KPACK * DDIM + (size_t)k4 * DDIM + o] = packed;
}

// ---------------------------------------------------------------------------
// 3. per-token int8 absmax quantization. One wave per 512-elem row.
// ---------------------------------------------------------------------------
__global__ __launch_bounds__(256) void aquant_kernel(
    const float* __restrict__ x, int* __restrict__ xq, float* __restrict__ sx) {
  int wid = threadIdx.x >> 6, lane = threadIdx.x & 63;
  int row = blockIdx.x * 4 + wid;
  const float* xr = x + (size_t)row * DDIM;
  float4 a = ((const float4*)xr)[lane];        // k = 4*lane .. +3
  float4 b = ((const float4*)xr)[64 + lane];   // k = 256+4*lane .. +3
  float amax = fmaxf(fmaxf(fmaxf(fabsf(a.x), fabsf(a.y)), fmaxf(fabsf(a.z), fabsf(a.w))),
                     fmaxf(fmaxf(fabsf(b.x), fabsf(b.y)), fmaxf(fabsf(b.z), fabsf(b.w))));
  for (int off = 32; off > 0; off >>= 1) amax = fmaxf(amax, __shfl_xor(amax, off, 64));
  float aa = fmaxf(amax, EPSQ);
  float scale = 127.0f / aa;
  int p0 = q8(a.x, scale) | (q8(a.y, scale) << 8) | (q8(a.z, scale) << 16) | (q8(a.w, scale) << 24);
  int p1 = q8(b.x, scale) | (q8(b.y, scale) << 8) | (q8(b.z, scale) << 16) | (q8(b.w, scale) << 24);
  xq[(size_t)row * KPACK + lane]      = p0;    // k4 = lane
  xq[(size_t)row * KPACK + 64 + lane] = p1;    // k4 = 64+lane
  if (lane == 0) sx[row] = aa * (1.0f / 127.0f);
}

// ---------------------------------------------------------------------------
// 4. int8 x ternary GEMM -> f16. grid (1024, 4, 3), block 256.
//    mats 0,1 (Q,K): natural [row][dim]. mat 2 (V): tiled-transposed
//    vT[b][kt=srow>>5][dim][srow&31] so each flash V-tile is contiguous 32 KB.
// ---------------------------------------------------------------------------
__global__ __launch_bounds__(256) void qkv_gemm_kernel(
    const int* __restrict__ xq, const int* __restrict__ wp,
    const float* __restrict__ sx, const float* __restrict__ mw,
    _Float16* __restrict__ qkv) {
  __shared__ int xs[16][KPACK];
  int tid = threadIdx.x;
  int r0  = blockIdx.x * 16;
  int ocl = tid & 127;
  int rg  = tid >> 7;
  int oc  = blockIdx.y * 128 + ocl;
  int mat = blockIdx.z;

  #pragma unroll
  for (int i = 0; i < 8; i++) {
    int e = i * 256 + tid;
    ((int*)xs)[e] = xq[(size_t)r0 * KPACK + e];
  }
  __syncthreads();

  const int* wcol = wp + (size_t)mat * KPACK * DDIM + oc;
  int acc[8] = {0, 0, 0, 0, 0, 0, 0, 0};
  #pragma unroll 4
  for (int k4 = 0; k4 < KPACK; k4++) {
    int wv = wcol[(size_t)k4 * DDIM];
    #pragma unroll
    for (int rr = 0; rr < 8; rr++)
      acc[rr] = dot4(xs[rg * 8 + rr][k4], wv, acc[rr]);
  }
  float mval = fmaxf(mw[mat] * (1.0f / 262144.0f), EPSQ);
  if (mat < 2) {
    _Float16* outb = qkv + (size_t)mat * NROW * DDIM;
    #pragma unroll
    for (int rr = 0; rr < 8; rr++) {
      int row = r0 + rg * 8 + rr;
      outb[(size_t)row * DDIM + oc] = (_Float16)((float)acc[rr] * sx[row] * mval);
    }
  } else {
    _Float16* vT = qkv + (size_t)2 * NROW * DDIM;
    int b = r0 >> 11;                    // rows r0..r0+15 in one batch (16 | 2048)
    int srow0 = (r0 & 2047) + rg * 8;    // 8 consecutive keys, same 32-block
    int kt = srow0 >> 5, kin = srow0 & 31;
    half8 hv;
    #pragma unroll
    for (int rr = 0; rr < 8; rr++) {
      int row = r0 + rg * 8 + rr;
      hv[rr] = (_Float16)((float)acc[rr] * sx[row] * mval);
    }
    *(half8*)(vT + ((((size_t)b * 64 + kt) * 512 + oc) * 32 + kin)) = hv;
  }
}

// ---------------------------------------------------------------------------
// 5. f16 MFMA flash attention, causal, scale 8^-0.5.
//    512 thr = 8 waves, BM=64, BN=32, grid (32,8), 2 complementary phases.
//    K and V^T both staged via async DMA, double-buffered. Ps32/Pf16 aliased
//    (same-wave reader/writer => no extra barrier). MFMA layouts as r4/r5.
// ---------------------------------------------------------------------------
__global__ __launch_bounds__(512, 2) void flash_kernel(
    const _Float16* __restrict__ q, const _Float16* __restrict__ k,
    const _Float16* __restrict__ vT, float* __restrict__ out) {
  __shared__ __align__(16) _Float16 Ksh[2][32][520];  // 66,560 B (DMA rows)
  __shared__ __align__(16) _Float16 VtL[2][512][32];  // 65,536 B (DMA linear)
  __shared__ __align__(16) float    PsU[64 * 34];     // 8,704 B; alias Pf16 stride 68
  __shared__ float alpha_l[64];
  __shared__ float invl_l[64];

  const int tid  = threadIdx.x;
  const int w    = tid >> 6;        // 0..7
  const int lane = tid & 63;
  const int quad = lane >> 4;
  const int col  = lane & 15;
  const int rt   = w & 3;           // score row-tile
  const int kh   = w >> 2;          // score key-half
  const int smrow = tid >> 3;       // softmax row 0..63
  const int sme   = tid & 7;        // softmax key group 0..7
  const int d0  = w * 64;           // PV dim slice
  _Float16* Pf = (_Float16*)PsU;

  const int qi = blockIdx.x, batch = blockIdx.y;

  for (int ph = 0; ph < 2; ph++) {
    const int qt = ph ? (31 - qi) : qi;
    const int bb = ph ? (batch ^ 1) : batch;
    const int qrow0 = qt * 64;
    const size_t bbase = (size_t)bb * SEQ * DDIM;
    const _Float16* kb_p = k + bbase;
    const _Float16* vt_p = vT + (size_t)bb * 64 * 512 * 32;  // [kt][dim][key]

    // Q A-frags in registers (rows qrow0 + rt*16 + col)
    half8 qfrag[16];
    {
      const _Float16* qrow_p = q + bbase + (size_t)(qrow0 + rt * 16 + col) * DDIM;
      #pragma unroll
      for (int s = 0; s < 16; s++)
        qfrag[s] = *(const half8*)(qrow_p + s * 32 + quad * 8);
    }

    float m_run = -INFINITY, l_run = 0.f;
    f32x4 o[4][4];
    #pragma unroll
    for (int a = 0; a < 4; a++)
      #pragma unroll
      for (int b = 0; b < 4; b++) o[a][b] = (f32x4)(0.f);

    const int ntiles = 2 * (qt + 1);

    // prologue: DMA tile 0 into buf 0
    #pragma unroll
    for (int i = 0; i < 4; i++)
      gld_lds16(kb_p + (size_t)(w * 4 + i) * DDIM + lane * 8, &Ksh[0][w * 4 + i][0]);
    #pragma unroll
    for (int i = 0; i < 4; i++)
      gld_lds16(vt_p + (size_t)(w * 64 + i * 16) * 32 + lane * 8, &VtL[0][w * 64 + i * 16][0]);
    __syncthreads();

    for (int kt = 0; kt < ntiles; kt++) {
      const int cur = kt & 1, nxt = cur ^ 1;
      const int kb0 = kt * 32;

      // prefetch tile kt+1 (drains at barrier B, covered by scores phase)
      if (kt + 1 < ntiles) {
        const int kb1 = kb0 + 32;
        #pragma unroll
        for (int i = 0; i < 4; i++)
          gld_lds16(kb_p + (size_t)(kb1 + w * 4 + i) * DDIM + lane * 8,
                    &Ksh[nxt][w * 4 + i][0]);
        const _Float16* vtile = vt_p + (size_t)(kt + 1) * 512 * 32;
        #pragma unroll
        for (int i = 0; i < 4; i++)
          gld_lds16(vtile + (size_t)(w * 64 + i * 16) * 32 + lane * 8,
                    &VtL[nxt][w * 64 + i * 16][0]);
      }

      // ---- scores: wave (rt,kh): rows rt*16..+15 x keys kb0+kh*16..+15 ----
      {
        f32x4 c = (f32x4)(0.f);
        #pragma unroll
        for (int s = 0; s < 16; s++) {
          half8 b = *(const half8*)&Ksh[cur][kh * 16 + col][s * 32 + quad * 8];
          c = __builtin_amdgcn_mfma_f32_16x16x32_f16(qfrag[s], b, c, 0, 0, 0);
        }
        #pragma unroll
        for (int reg = 0; reg < 4; reg++)
          PsU[(rt * 16 + quad * 4 + reg) * 34 + kh * 16 + col] = c[reg];
      }
      __syncthreads();   // B: scores ready (drains DMA prefetch)

      // ---- softmax: thread (smrow, sme) handles keys sme*4..+3 ----
      {
        const int qrow = qrow0 + smrow;
        float sv[4];
        #pragma unroll
        for (int i = 0; i < 4; i++) {
          float s = PsU[smrow * 34 + sme * 4 + i] * FSCALE;
          if (kb0 + sme * 4 + i > qrow) s = -INFINITY;
          sv[i] = s;
        }
        float mx = fmaxf(fmaxf(sv[0], sv[1]), fmaxf(sv[2], sv[3]));
        #pragma unroll
        for (int m = 1; m <= 4; m <<= 1) mx = fmaxf(mx, __shfl_xor(mx, m, 64));
        float mn = fmaxf(m_run, mx);
        float al = __expf(m_run - mn);
        half4 p4;
        float rs = 0.f;
        #pragma unroll
        for (int i = 0; i < 4; i++) {
          float p = __expf(sv[i] - mn);
          rs += p;
          p4[i] = (_Float16)p;
        }
        #pragma unroll
        for (int m = 1; m <= 4; m <<= 1) rs += __shfl_xor(rs, m, 64);
        l_run = l_run * al + rs;
        m_run = mn;
        // aliased write: same-wave containment => no race with PsU reads above
        *(half4*)&Pf[smrow * 68 + sme * 4] = p4;
        if (sme == 0) alpha_l[smrow] = al;
      }
      __syncthreads();   // C: Pf16 + alpha ready

      // ---- PV: wave w owns dims d0..d0+63 for all 64 rows ----
      {
        half8 ap[4];
        f32x4 af[4];
        #pragma unroll
        for (int r2 = 0; r2 < 4; r2++) {
          union { half8 v; half4 h[2]; } u;
          u.h[0] = *(const half4*)&Pf[(r2 * 16 + col) * 68 + quad * 8];
          u.h[1] = *(const half4*)&Pf[(r2 * 16 + col) * 68 + quad * 8 + 4];
          ap[r2] = u.v;
          af[r2] = *(const f32x4*)&alpha_l[r2 * 16 + quad * 4];
        }
        #pragma unroll
        for (int r2 = 0; r2 < 4; r2++)
          #pragma unroll
          for (int ct = 0; ct < 4; ct++)
            o[r2][ct] *= af[r2];
        #pragma unroll
        for (int ct = 0; ct < 4; ct++) {
          half8 bv = *(const half8*)&VtL[cur][d0 + ct * 16 + col][quad * 8];
          #pragma unroll
          for (int r2 = 0; r2 < 4; r2++)
            o[r2][ct] = __builtin_amdgcn_mfma_f32_16x16x32_f16(ap[r2], bv, o[r2][ct], 0, 0, 0);
        }
      }
      __syncthreads();   // D: PV done; bufs swap, PsU reusable
    }

    // ---- finalize ----
    if (sme == 0) invl_l[smrow] = 1.0f / l_run;
    __syncthreads();
    #pragma unroll
    for (int r2 = 0; r2 < 4; r2++) {
      f32x4 iv = *(const f32x4*)&invl_l[r2 * 16 + quad * 4];
      #pragma unroll
      for (int ct = 0; ct < 4; ct++) {
        #pragma unroll
        for (int e = 0; e < 4; e++) {
          out[((size_t)bb * SEQ + qrow0 + r2 * 16 + quad * 4 + e) * DDIM
              + d0 + ct * 16 + col] = o[r2][ct][e] * iv[e];
        }
      }
    }
    __syncthreads();   // protect LDS before next phase's prologue
  }
}

// ---------------------------------------------------------------------------
extern "C" void kernel_launch(void* const* d_in, const int* in_sizes, int n_in,
                              void* d_out, int out_size, void* d_ws, size_t ws_size,
                              hipStream_t stream) {
  const float* x  = (const float*)d_in[0];
  const float* Wq = (const float*)d_in[1];
  const float* Wk = (const float*)d_in[2];
  const float* Wv = (const float*)d_in[3];
  float* out = (float*)d_out;
  char* ws = (char*)d_ws;

  float* mw  = (float*)(ws + OFF_M);
  int*   wp  = (int*)(ws + OFF_WP);
  int*   xq  = (int*)(ws + OFF_XQ);
  float* sx  = (float*)(ws + OFF_SX);
  _Float16* qkv = (_Float16*)(ws + OFF_QKV);
  _Float16* qf  = qkv;
  _Float16* kf  = qkv + (size_t)NROW * DDIM;
  _Float16* vTf = qkv + 2 * (size_t)NROW * DDIM;

  hipMemsetAsync(mw, 0, 16, stream);
  wsum_kernel<<<dim3(32, 3), 256, 0, stream>>>(Wq, Wk, Wv, mw);
  wquant_kernel<<<768, 256, 0, stream>>>(Wq, Wk, Wv, mw, wp);
  aquant_kernel<<<4096, 256, 0, stream>>>(x, xq, sx);
  qkv_gemm_kernel<<<dim3(1024, 4, 3), 256, 0, stream>>>(xq, wp, sx, mw, qkv);
  flash_kernel<<<dim3(32, 8), 512, 0, stream>>>(qf, kf, vTf, out);
}